// Round 1
// 609.257 us; speedup vs baseline: 1.0593x; 1.0593x over previous
//
#include <hip/hip_runtime.h>

// Problem constants (fixed by setup_inputs)
#define BS   4
#define NH   8
#define SEQ  2048
#define DK   64
#define NP   129      // max_pos + 1
#define QS_PITCH 68   // q-row LDS pitch in floats: 272 B (16B-aligned, bank-spread)
#define PPAD 132      // proj LDS row pitch (132 mod 32 = 4 -> per-h bank offset)

typedef float v4f __attribute__((ext_vector_type(4)));
typedef int   v4i __attribute__((ext_vector_type(4)));

// ---------------------------------------------------------------------------
// Fused kernel: one block per (b,i).
//   Phase 0: issue dist-row NT loads (independent of everything else).
//   Phase 1: stage the 8 q rows (b,*,i) into LDS (2.2 KB).
//   Phase 2: compute proj[h][p] = dot(q_row(h), w[p]) for all 8*129 pairs.
//            Thread t owns (h = t&7, p = t>>3 + 32*it). q row cached in 16 v4f
//            registers (read LDS once); w row comes from L1 (33 KB, resident;
//            only 8 distinct rows per wave-load -> broadcast-friendly).
//   Phase 3: gather by clamped dist, stream 8 output rows with NT float4
//            stores (unchanged from the verified 2-kernel version).
// No workspace use at all.
// ---------------------------------------------------------------------------
__global__ __launch_bounds__(256) void fused_kernel(
    const float* __restrict__ q,     // [BS,NH,SEQ,DK]
    const int*   __restrict__ dist,  // [BS,SEQ,SEQ]
    const float* __restrict__ w,     // [NP,DK]
    float*       __restrict__ out)   // [BS,NH,SEQ,SEQ]
{
    __shared__ __align__(16) float qs[NH * QS_PITCH];   // 2176 B
    __shared__ __align__(16) float proj[NH * PPAD];     // 4224 B

    const int tid = threadIdx.x;
    const int bi  = blockIdx.x;          // b*SEQ + i
    const int b   = bi >> 11;
    const int i   = bi & (SEQ - 1);

    // Phase 0: dist-row loads early (latency hidden under phases 1-2)
    const v4i* dist4 = (const v4i*)(dist + (size_t)bi * SEQ);
    const v4i dd0 = __builtin_nontemporal_load(&dist4[tid]);
    const v4i dd1 = __builtin_nontemporal_load(&dist4[256 + tid]);

    // Phase 1: stage 8 q rows -> LDS. 128 v4f total, threads 0..127.
    if (tid < 128) {
        const int h = tid >> 4;
        const int c = tid & 15;
        const v4f v = *(const v4f*)(q + (((size_t)(b * NH + h) * SEQ) + i) * DK + 4 * c);
        *(v4f*)&qs[h * QS_PITCH + 4 * c] = v;
    }
    __syncthreads();

    // Phase 2: 1032 dots = 256 threads * 4 + 8 tail (p = 128).
    {
        const int h     = tid & 7;
        const int pbase = tid >> 3;      // 0..31
        v4f qr[16];
        #pragma unroll
        for (int k = 0; k < 16; ++k)
            qr[k] = *(const v4f*)&qs[h * QS_PITCH + 4 * k];  // bank-spread, 8-way bcast

        #pragma unroll
        for (int it = 0; it < 4; ++it) {
            const int p = pbase + 32 * it;
            const v4f* wrow = (const v4f*)(w + p * DK);
            v4f s = {0.f, 0.f, 0.f, 0.f};
            #pragma unroll
            for (int k = 0; k < 16; ++k) s += qr[k] * wrow[k];
            proj[h * PPAD + p] = s.x + s.y + s.z + s.w;
        }
        if (tid < 8) {                   // tail position p = 128, h = tid
            const v4f* wrow = (const v4f*)(w + 128 * DK);
            v4f s = {0.f, 0.f, 0.f, 0.f};
            #pragma unroll
            for (int k = 0; k < 16; ++k) s += qr[k] * wrow[k];
            proj[h * PPAD + 128] = s.x + s.y + s.z + s.w;
        }
    }
    __syncthreads();

    // Phase 3: gather + streamed stores: out[((b*NH+h)*SEQ + i)*SEQ + j]
    const size_t obase = ((size_t)(b * NH) * SEQ + i) * SEQ;
    #pragma unroll
    for (int it = 0; it < 2; ++it) {
        const v4i dd = (it == 0) ? dd0 : dd1;
        const int j0 = (it * 256 + tid) << 2;
        const int px = min(dd.x, NP - 1);
        const int py = min(dd.y, NP - 1);
        const int pz = min(dd.z, NP - 1);
        const int pw = min(dd.w, NP - 1);
        #pragma unroll
        for (int h = 0; h < NH; ++h) {
            const float* pr = &proj[h * PPAD];
            v4f v;
            v.x = pr[px];
            v.y = pr[py];
            v.z = pr[pz];
            v.w = pr[pw];
            __builtin_nontemporal_store(
                v, (v4f*)(out + obase + (size_t)h * ((size_t)SEQ * SEQ) + j0));
        }
    }
}

extern "C" void kernel_launch(void* const* d_in, const int* in_sizes, int n_in,
                              void* d_out, int out_size, void* d_ws, size_t ws_size,
                              hipStream_t stream) {
    const float* q    = (const float*)d_in[0];
    const int*   dist = (const int*)d_in[1];
    const float* w    = (const float*)d_in[2];
    float*       out  = (float*)d_out;
    (void)d_ws; (void)ws_size;

    fused_kernel<<<BS * SEQ, 256, 0, stream>>>(q, dist, w, out);
}